// Round 6
// baseline (1483.383 us; speedup 1.0000x reference)
//
#include <hip/hip_runtime.h>

typedef unsigned short u16;
typedef unsigned int   u32;
typedef __attribute__((ext_vector_type(8))) short short8;
typedef __attribute__((ext_vector_type(4))) float f32x4;

#define DEV static __device__ __forceinline__

DEV u16 f2bf(float x) {
  union { float f; u32 u; } c; c.f = x;
  u32 r = c.u + 0x7fffu + ((c.u >> 16) & 1u);
  return (u16)(r >> 16);
}

struct __align__(8) us4 { u16 a, b, c, d; };

DEV void gload16(const void* g, void* l) {
  __builtin_amdgcn_global_load_lds(
      (const __attribute__((address_space(1))) void*)g,
      (__attribute__((address_space(3))) void*)l, 16, 0, 0);
}

// ---------------------------------------------------------------------------
// GEMM: C[M,N] = A[M,K] (bf16) @ Bt[N,K]^T (bf16), 128x128 tile, BK=64,
// 4 waves (2x2 of 64x64), XOR-swizzled LDS via pre-swizzled global source
// (rule #21: linear LDS dest, inverse-swizzled global src, swizzled ds_read).
// T1 XCD-aware block swizzle over the x-y grid (all launches have
// gridDim.x*gridDim.y % 8 == 0, so the simple remap is bijective).
// K-range is split across gridDim.z (chunk must be a multiple of 64).
// EPI 0: +bias, scatter to Q/K/Vt bf16 layouts (QKV projection)
// EPI 1: +bias +resid(f32), store f32                (o-proj)
// EPI 2: +bias, relu, store bf16                     (FFN1)
// EPI 3: atomicAdd raw partial into outf (pre-initialized with bias+resid)
//        (FFN2 split-K)
// ---------------------------------------------------------------------------
template<int EPI>
__global__ __launch_bounds__(256)
void gemm_bt(const u16* __restrict__ A, const u16* __restrict__ Bt,
             const float* __restrict__ bias, const float* __restrict__ resid,
             float* __restrict__ outf, u16* __restrict__ outb,
             u16* __restrict__ q_out, u16* __restrict__ k_out, u16* __restrict__ vt_out,
             int M, int N, int K)
{
  __shared__ __align__(16) u16 As[128 * 64];
  __shared__ __align__(16) u16 Bs[128 * 64];
  const int tid = threadIdx.x;
  const int lane = tid & 63;
  const int wave = tid >> 6;
  const int wm = wave >> 1, wn = wave & 1;
  const int lo = lane & 15, hi = lane >> 4;

  // T1: XCD swizzle (bijective since nwg % 8 == 0 for every launch here)
  const int nwg = gridDim.x * gridDim.y;
  int bid = blockIdx.y * gridDim.x + blockIdx.x;
  bid = (bid & 7) * (nwg >> 3) + (bid >> 3);
  const int bm = (bid / gridDim.x) * 128;
  const int bn = (bid % gridDim.x) * 128;

  const int kchunk = K / gridDim.z;
  const int kbeg = blockIdx.z * kchunk;
  const int kend = kbeg + kchunk;

  f32x4 zero = {0.f, 0.f, 0.f, 0.f};
  f32x4 acc[4][4];
#pragma unroll
  for (int i = 0; i < 4; ++i)
#pragma unroll
    for (int j = 0; j < 4; ++j) acc[i][j] = zero;

  for (int k0 = kbeg; k0 < kend; k0 += 64) {
    // ---- stage A,B tiles (128x64 each) via global_load_lds, swizzled source
#pragma unroll
    for (int i = 0; i < 4; ++i) {
      int slot = i * 4096 + tid * 16;       // byte slot in LDS (lin dest)
      int row  = slot >> 7;                 // 128B per row (64 bf16)
      int c16  = (slot >> 4) & 7;
      int gc   = (c16 ^ (row & 7)) * 8;     // inverse-swizzled source col
      gload16(A  + (size_t)(bm + row) * K + k0 + gc,
              (char*)As + i * 4096 + wave * 1024);
      gload16(Bt + (size_t)(bn + row) * K + k0 + gc,
              (char*)Bs + i * 4096 + wave * 1024);
    }
    __syncthreads();
    // ---- compute: 2 x (k=32) MFMA slices, fragment k-chunk = kk*4+hi
#pragma unroll
    for (int kk = 0; kk < 2; ++kk) {
      short8 a[4], b[4];
      int ks = kk * 4 + hi;
#pragma unroll
      for (int mi = 0; mi < 4; ++mi) {
        int row = wm * 64 + mi * 16 + lo;
        a[mi] = *(const short8*)&As[row * 64 + ((ks ^ (row & 7)) * 8)];
      }
#pragma unroll
      for (int ni = 0; ni < 4; ++ni) {
        int row = wn * 64 + ni * 16 + lo;
        b[ni] = *(const short8*)&Bs[row * 64 + ((ks ^ (row & 7)) * 8)];
      }
#pragma unroll
      for (int mi = 0; mi < 4; ++mi)
#pragma unroll
        for (int ni = 0; ni < 4; ++ni)
          acc[mi][ni] = __builtin_amdgcn_mfma_f32_16x16x32_bf16(
              a[mi], b[ni], acc[mi][ni], 0, 0, 0);
    }
    __syncthreads();
  }

  // ---- epilogue: C row = bm+wm*64+mi*16+hi*4+r, col = bn+wn*64+ni*16+lo
#pragma unroll
  for (int mi = 0; mi < 4; ++mi) {
#pragma unroll
    for (int ni = 0; ni < 4; ++ni) {
      int col = bn + wn * 64 + ni * 16 + lo;
#pragma unroll
      for (int r = 0; r < 4; ++r) {
        int row = bm + wm * 64 + mi * 16 + hi * 4 + r;
        float v = acc[mi][ni][r];
        if (EPI == 0) {
          v += bias[col];
          int qkv = col >> 10, wc = col & 1023, h = wc >> 6, hd = wc & 63;
          int b_ = row >> 11, t = row & 2047;
          u16 bv = f2bf(v);
          if (qkv == 0)
            q_out[((size_t)((b_ * 16 + h) * 2048 + t)) * 64 + hd] = bv;
          else if (qkv == 1)
            k_out[((size_t)((b_ * 16 + h) * 2048 + t)) * 64 + hd] = bv;
          else
            vt_out[((size_t)((b_ * 16 + h) * 64 + hd)) * 2048 + t] = bv;
        } else if (EPI == 1) {
          v += bias[col] + resid[(size_t)row * N + col];
          outf[(size_t)row * N + col] = v;
        } else if (EPI == 2) {
          v += bias[col];
          v = v > 0.f ? v : 0.f;
          outb[(size_t)row * N + col] = f2bf(v);
        } else {
          atomicAdd(&outf[(size_t)row * N + col], v);
        }
      }
    }
  }
}

// ---------------------------------------------------------------------------
// Flash attention: one block per (bh, 64-row q-tile); 4 waves x 16 q-rows.
// K tile [64 kv][64 d], V tile (from Vt) [64 d][64 kv], both XOR-swizzled.
// Heavy-first: qt reversed so the costliest (most-kv) tiles dispatch first,
// leaving the cheap diagonal tiles to fill the tail.
// ---------------------------------------------------------------------------
__global__ __launch_bounds__(256)
void attn_kernel(const u16* __restrict__ Q, const u16* __restrict__ Kb,
                 const u16* __restrict__ Vt, u16* __restrict__ O)
{
  __shared__ __align__(16) u16 Ks[64 * 64];
  __shared__ __align__(16) u16 Vs[64 * 64];
  __shared__ __align__(16) u16 Pl[4][16 * 80];   // pad 80 -> 16B-aligned rows
  const int tid = threadIdx.x, lane = tid & 63, w = tid >> 6;
  const int lo = lane & 15, hi = lane >> 4;
  const int bh = blockIdx.y;
  const int qt = gridDim.x - 1 - blockIdx.x;     // heavy tiles first
  const int q0 = qt * 64;

  const size_t qbase = ((size_t)bh * 2048 + q0 + w * 16 + lo) * 64;
  short8 qf[2];
  qf[0] = *(const short8*)(Q + qbase + hi * 8);
  qf[1] = *(const short8*)(Q + qbase + 32 + hi * 8);

  float m[4]    = {-1e30f, -1e30f, -1e30f, -1e30f};
  float lsum[4] = {0.f, 0.f, 0.f, 0.f};
  f32x4 zero = {0.f, 0.f, 0.f, 0.f};
  f32x4 oacc[4];
#pragma unroll
  for (int i = 0; i < 4; ++i) oacc[i] = zero;

  const int smax = qt;  // diagonal kv-tile
  for (int s = 0; s <= smax; ++s) {
#pragma unroll
    for (int i = 0; i < 2; ++i) {
      int slot = i * 4096 + tid * 16;
      int row  = slot >> 7;
      int gc   = (((slot >> 4) & 7) ^ (row & 7)) * 8;
      gload16(Kb + ((size_t)bh * 2048 + s * 64 + row) * 64 + gc,
              (char*)Ks + i * 4096 + w * 1024);
      gload16(Vt + ((size_t)bh * 64 + row) * 2048 + s * 64 + gc,
              (char*)Vs + i * 4096 + w * 1024);
    }
    __syncthreads();

    f32x4 sacc[4];
#pragma unroll
    for (int i = 0; i < 4; ++i) sacc[i] = zero;
#pragma unroll
    for (int ni = 0; ni < 4; ++ni)
#pragma unroll
      for (int kk = 0; kk < 2; ++kk) {
        int row = ni * 16 + lo;
        short8 kf = *(const short8*)&Ks[row * 64 + (((kk * 4 + hi) ^ (row & 7)) * 8)];
        sacc[ni] = __builtin_amdgcn_mfma_f32_16x16x32_bf16(qf[kk], kf, sacc[ni], 0, 0, 0);
      }

    const bool diag = (s == smax);
    float pvv[4][4];
#pragma unroll
    for (int r = 0; r < 4; ++r) {
      int qrow = q0 + w * 16 + hi * 4 + r;
      float mx = -1e30f;
#pragma unroll
      for (int ni = 0; ni < 4; ++ni) {
        float v = sacc[ni][r] * 0.125f;
        int kv = s * 64 + ni * 16 + lo;
        if (diag && kv > qrow) v = -1e30f;
        pvv[ni][r] = v;
        mx = fmaxf(mx, v);
      }
#pragma unroll
      for (int msk = 1; msk < 16; msk <<= 1) mx = fmaxf(mx, __shfl_xor(mx, msk));
      float mnew = fmaxf(m[r], mx);
      float corr = __expf(m[r] - mnew);
      m[r] = mnew;
      float rs = 0.f;
#pragma unroll
      for (int ni = 0; ni < 4; ++ni) {
        float p = __expf(pvv[ni][r] - mnew);
        pvv[ni][r] = p;
        rs += p;
      }
#pragma unroll
      for (int msk = 1; msk < 16; msk <<= 1) rs += __shfl_xor(rs, msk);
      lsum[r] = lsum[r] * corr + rs;
#pragma unroll
      for (int nd = 0; nd < 4; ++nd) oacc[nd][r] *= corr;
    }

#pragma unroll
    for (int ni = 0; ni < 4; ++ni)
#pragma unroll
      for (int r = 0; r < 4; ++r)
        Pl[w][(hi * 4 + r) * 80 + ni * 16 + lo] = f2bf(pvv[ni][r]);

#pragma unroll
    for (int kk = 0; kk < 2; ++kk) {
      short8 pa = *(const short8*)&Pl[w][lo * 80 + kk * 32 + hi * 8];
#pragma unroll
      for (int nd = 0; nd < 4; ++nd) {
        int row = nd * 16 + lo;
        short8 vf = *(const short8*)&Vs[row * 64 + (((kk * 4 + hi) ^ (row & 7)) * 8)];
        oacc[nd] = __builtin_amdgcn_mfma_f32_16x16x32_bf16(pa, vf, oacc[nd], 0, 0, 0);
      }
    }
    __syncthreads();
  }

  const int b_ = bh >> 4, h_ = bh & 15;
#pragma unroll
  for (int r = 0; r < 4; ++r) {
    int t = q0 + w * 16 + hi * 4 + r;
    float inv = 1.f / lsum[r];
    size_t base = ((size_t)b_ * 2048 + t) * 1024 + h_ * 64;
#pragma unroll
    for (int nd = 0; nd < 4; ++nd)
      O[base + nd * 16 + lo] = f2bf(oacc[nd][r] * inv);
  }
}

// ---------------------------------------------------------------------------
// LayerNorm over rows of 1024; optional bf16 secondary output; optional
// split-K seed output (seed_out[row][col] = o + seed_bias[col]) which fuses
// the former out_init kernel into LN1.
// Safe in-place (outf may == in): each thread reads its own 16B before
// writing the same 16B; rows are block-exclusive.
// ---------------------------------------------------------------------------
__global__ __launch_bounds__(256)
void ln_kernel(const float* __restrict__ in, const float* __restrict__ g,
               const float* __restrict__ bp, float* __restrict__ outf,
               u16* __restrict__ outb,
               float* __restrict__ seed_out, const float* __restrict__ seed_bias)
{
  const int row = blockIdx.x, t = threadIdx.x;
  const f32x4 v = *(const f32x4*)(in + (size_t)row * 1024 + t * 4);
  float s  = v[0] + v[1] + v[2] + v[3];
  float sq = v[0] * v[0] + v[1] * v[1] + v[2] * v[2] + v[3] * v[3];
#pragma unroll
  for (int off = 32; off; off >>= 1) {
    s  += __shfl_down(s, off);
    sq += __shfl_down(sq, off);
  }
  __shared__ float red[8];
  const int lane = t & 63, w = t >> 6;
  if (lane == 0) { red[w] = s; red[4 + w] = sq; }
  __syncthreads();
  s  = red[0] + red[1] + red[2] + red[3];
  sq = red[4] + red[5] + red[6] + red[7];
  float mu  = s * (1.f / 1024.f);
  float var = sq * (1.f / 1024.f) - mu * mu;
  float rstd = rsqrtf(var + 1e-5f);
  const f32x4 gv = *(const f32x4*)(g + t * 4);
  const f32x4 bv = *(const f32x4*)(bp + t * 4);
  f32x4 o;
#pragma unroll
  for (int j = 0; j < 4; ++j) o[j] = (v[j] - mu) * rstd * gv[j] + bv[j];
  *(f32x4*)(outf + (size_t)row * 1024 + t * 4) = o;
  if (outb) {
    us4 ob = {f2bf(o[0]), f2bf(o[1]), f2bf(o[2]), f2bf(o[3])};
    *(us4*)(outb + (size_t)row * 1024 + t * 4) = ob;
  }
  if (seed_out) {
    const f32x4 sb = *(const f32x4*)(seed_bias + t * 4);
    f32x4 so = {o[0] + sb[0], o[1] + sb[1], o[2] + sb[2], o[3] + sb[3]};
    *(f32x4*)(seed_out + (size_t)row * 1024 + t * 4) = so;
  }
}

// ---------------------------------------------------------------------------
// Packing / conversion kernels
// ---------------------------------------------------------------------------
__global__ __launch_bounds__(256)
void cvt_bf16(const float* __restrict__ src, u16* __restrict__ dst, int n4)
{
  int i = blockIdx.x * 256 + threadIdx.x;
  if (i < n4) {
    f32x4 v = *(const f32x4*)(src + (size_t)i * 4);
    us4 o = {f2bf(v[0]), f2bf(v[1]), f2bf(v[2]), f2bf(v[3])};
    *(us4*)(dst + (size_t)i * 4) = o;
  }
}

// src[R][C] f32 -> dst[C][R] bf16 (tiled 64x64)
__global__ __launch_bounds__(256)
void transpose_cvt(const float* __restrict__ src, u16* __restrict__ dst, int R, int C)
{
  __shared__ float tile[64][65];
  const int c0 = blockIdx.x * 64, r0 = blockIdx.y * 64;
  const int t = threadIdx.x;
  const int rl = t >> 4, c4 = (t & 15) * 4;
#pragma unroll
  for (int i = 0; i < 4; ++i) {
    f32x4 v = *(const f32x4*)(src + (size_t)(r0 + rl + i * 16) * C + c0 + c4);
    tile[rl + i * 16][c4 + 0] = v[0];
    tile[rl + i * 16][c4 + 1] = v[1];
    tile[rl + i * 16][c4 + 2] = v[2];
    tile[rl + i * 16][c4 + 3] = v[3];
  }
  __syncthreads();
#pragma unroll
  for (int j = 0; j < 16; ++j) {
    int o = t + j * 256;
    int c = o >> 6, r = o & 63;
    dst[(size_t)(c0 + c) * R + r0 + r] = f2bf(tile[r][c]);
  }
}

// Wq/Wk/Wv [H][1024][64] -> Wt[(qkv*1024 + h*64 + hd)][k]
__global__ __launch_bounds__(256)
void qkv_pack(const float* __restrict__ Wq, const float* __restrict__ Wk,
              const float* __restrict__ Wv, u16* __restrict__ Wt)
{
  const float* src = blockIdx.z == 0 ? Wq : (blockIdx.z == 1 ? Wk : Wv);
  src += (size_t)blockIdx.y * 1024 * 64;
  __shared__ float tile[64][65];
  const int k0 = blockIdx.x * 64;
  const int t = threadIdx.x;
  const int rl = t >> 4, c4 = (t & 15) * 4;
#pragma unroll
  for (int i = 0; i < 4; ++i) {
    f32x4 v = *(const f32x4*)(src + (size_t)(k0 + rl + i * 16) * 64 + c4);
    tile[rl + i * 16][c4 + 0] = v[0];
    tile[rl + i * 16][c4 + 1] = v[1];
    tile[rl + i * 16][c4 + 2] = v[2];
    tile[rl + i * 16][c4 + 3] = v[3];
  }
  __syncthreads();
  size_t nbase = (size_t)blockIdx.z * 1024 + blockIdx.y * 64;
#pragma unroll
  for (int j = 0; j < 16; ++j) {
    int o = t + j * 256;
    int hd = o >> 6, r = o & 63;
    Wt[(nbase + hd) * 1024 + k0 + r] = f2bf(tile[r][hd]);
  }
}

__global__ void bias_pack(const float* __restrict__ bq, const float* __restrict__ bk,
                          const float* __restrict__ bv, float* __restrict__ out)
{
  int i = blockIdx.x * 256 + threadIdx.x;
  if (i < 3072) {
    const float* s = (i >> 10) == 0 ? bq : ((i >> 10) == 1 ? bk : bv);
    out[i] = s[i & 1023];
  }
}

// ---------------------------------------------------------------------------
// Workspace layout (MB offsets) — weights fixed low, scratch high:
//   [0,6)    Wqkvt     [6,7)  bqkv    [7,9)  Wot
//   [9,41)   W1t       [41,73) W2t
//   [73,89)  out1b     [89,121) y1 (f32; LN1 in-place)
//   [121,..) scratch:
//     phases QKV/attn/o-proj: Xb[121,137) Qb[137,153) Kb[153,169)
//                             Vt[169,185) attnb[185,201)
//     FFN: h = [121, 121 + 256/nchunks MB)  (overlaps Xb..attnb, all dead)
//   ws requirement: nchunks=1 -> 377 MB; nchunks=4 -> 201 MB.
//   nchunks chosen from ws_size at launch (constant across graph replays).
// ---------------------------------------------------------------------------
extern "C" void kernel_launch(void* const* d_in, const int* in_sizes, int n_in,
                              void* d_out, int out_size, void* d_ws, size_t ws_size,
                              hipStream_t stream)
{
  const float* x    = (const float*)d_in[0];
  const float* Wq   = (const float*)d_in[1];
  const float* bq   = (const float*)d_in[2];
  const float* Wk   = (const float*)d_in[3];
  const float* bk   = (const float*)d_in[4];
  const float* Wv   = (const float*)d_in[5];
  const float* bv   = (const float*)d_in[6];
  const float* Wo   = (const float*)d_in[7];
  const float* bo   = (const float*)d_in[8];
  const float* ln1g = (const float*)d_in[9];
  const float* ln1b = (const float*)d_in[10];
  const float* W1   = (const float*)d_in[11];
  const float* b1   = (const float*)d_in[12];
  const float* W2   = (const float*)d_in[13];
  const float* b2   = (const float*)d_in[14];
  const float* ln2g = (const float*)d_in[15];
  const float* ln2b = (const float*)d_in[16];
  float* out = (float*)d_out;

  char* ws = (char*)d_ws;
  const size_t MB = 1ull << 20;
  u16*   Wqkvt = (u16*)(ws + 0);
  float* bqkv  = (float*)(ws + 6 * MB);
  u16*   Wot   = (u16*)(ws + 7 * MB);
  u16*   W1t   = (u16*)(ws + 9 * MB);
  u16*   W2t   = (u16*)(ws + 41 * MB);
  u16*   out1b = (u16*)(ws + 73 * MB);
  float* y1    = (float*)(ws + 89 * MB);    // LN1 runs in-place here
  u16*   Xb    = (u16*)(ws + 121 * MB);
  u16*   Qb    = (u16*)(ws + 137 * MB);
  u16*   Kb    = (u16*)(ws + 153 * MB);
  u16*   Vt    = (u16*)(ws + 169 * MB);
  u16*   attnb = (u16*)(ws + 185 * MB);
  u16*   h_buf = (u16*)(ws + 121 * MB);     // FFN hidden chunk (scratch reuse)
  float* y2    = out;                       // FFN2 -> d_out, LN2 in-place

  // FFN chunking: full-size h (256 MB) if ws allows, else 4 chunks of 64 MB.
  const int nchunks = (ws_size >= 377 * MB) ? 1 : 4;
  const int Mc      = 8192 / nchunks;       // rows per chunk
  const int zsplit  = (nchunks == 1) ? 4 : 8;

  // 1. input/weight conversion
  cvt_bf16<<<8192, 256, 0, stream>>>(x, Xb, 8192 * 1024 / 4);
  qkv_pack<<<dim3(16, 16, 3), 256, 0, stream>>>(Wq, Wk, Wv, Wqkvt);
  bias_pack<<<12, 256, 0, stream>>>(bq, bk, bv, bqkv);
  transpose_cvt<<<dim3(16, 16), 256, 0, stream>>>(Wo, Wot, 1024, 1024);
  transpose_cvt<<<dim3(256, 16), 256, 0, stream>>>(W1, W1t, 1024, 16384);
  transpose_cvt<<<dim3(16, 256), 256, 0, stream>>>(W2, W2t, 16384, 1024);

  // 2. QKV projection (scatter epilogue)
  gemm_bt<0><<<dim3(24, 64), 256, 0, stream>>>(Xb, Wqkvt, bqkv, nullptr,
      nullptr, nullptr, Qb, Kb, Vt, 8192, 3072, 1024);

  // 3. causal flash attention (heavy-first q-tile order)
  attn_kernel<<<dim3(32, 64), 256, 0, stream>>>(Qb, Kb, Vt, attnb);

  // 4. output projection + bo + x residual -> y1 (f32)
  gemm_bt<1><<<dim3(8, 64), 256, 0, stream>>>(attnb, Wot, bo, x,
      y1, nullptr, nullptr, nullptr, nullptr, 8192, 1024, 1024);

  // 5. LN1 (in-place on y1) -> out1f (=y1) + out1b (bf16) + FFN2 seed
  //    (d_out = out1 + b2, fused former out_init)
  ln_kernel<<<8192, 256, 0, stream>>>(y1, ln1g, ln1b, y1, out1b, y2, b2);

  // 6+7. FFN, chunked over M. Per chunk: FFN1 writes h chunk (bf16),
  //      FFN2 split-K atomically accumulates into the seeded d_out.
  //      Chunked h (64 MB) is L3-resident for the immediate FFN2 read.
  for (int c = 0; c < nchunks; ++c) {
    gemm_bt<2><<<dim3(128, Mc / 128), 256, 0, stream>>>(
        out1b + (size_t)c * Mc * 1024, W1t, b1, nullptr,
        nullptr, h_buf, nullptr, nullptr, nullptr, Mc, 16384, 1024);
    gemm_bt<3><<<dim3(8, Mc / 128, zsplit), 256, 0, stream>>>(
        h_buf, W2t, nullptr, nullptr,
        y2 + (size_t)c * Mc * 1024, nullptr, nullptr, nullptr, nullptr,
        Mc, 1024, 16384);
  }

  // 8. LN2 (in-place on d_out)
  ln_kernel<<<8192, 256, 0, stream>>>(y2, ln2g, ln2b, out, nullptr,
                                      nullptr, nullptr);

  (void)in_sizes; (void)n_in; (void)out_size;
}